// Round 4
// baseline (122.402 us; speedup 1.0000x reference)
//
#include <hip/hip_runtime.h>
#include <hip/hip_bf16.h>
#include <math.h>

constexpr int kB = 128;
constexpr int kT = 256;
constexpr int kC = 384;
constexpr int kH = 64;

using bf16x8 = __attribute__((ext_vector_type(8))) short;  // 8 bf16 = 4 VGPRs
using f32x4  = __attribute__((ext_vector_type(4))) float;

union BF4 { short4 s; __hip_bfloat162 h[2]; };

__device__ inline short4 cvt4(float4 a) {
    BF4 u;
    u.h[0] = __float22bfloat162_rn(float2{a.x, a.y});
    u.h[1] = __float22bfloat162_rn(float2{a.z, a.w});
    return u.s;
}
__device__ inline short bf1(float f) {
    __hip_bfloat16 h = __float2bfloat16(f);
    return *(short*)&h;
}

// ---------------------------------------------------------------------------
// Kernel 0: Wt[n][k] bf16, n in [0,192) = (w*64+h), k in [0,384).
// Wk rows pre-scaled by 384^-0.5 (k only feeds scores).
// ---------------------------------------------------------------------------
__global__ void prep_kernel(const float* __restrict__ Wq,
                            const float* __restrict__ Wk,
                            const float* __restrict__ Wv,
                            __hip_bfloat16* __restrict__ Wt) {
    int idx = blockIdx.x * 256 + threadIdx.x;     // [0, 192*384)
    int n = idx / kC, c = idx % kC;
    int w = n >> 6, h = n & 63;
    const float* W = (w == 0) ? Wq : (w == 1) ? Wk : Wv;
    float val = W[c * kH + h];
    if (w == 1) val *= 0.051031036307982884f;     // 384^-0.5
    Wt[idx] = __float2bfloat16(val);
}

// ---------------------------------------------------------------------------
// Kernel 1: projection GEMM (unchanged from round 3 — verified passing).
// 512 blocks x 256 threads; block = (q4, b), bid%8 == b%8 pins each batch's
// qkv to one XCD's L2 for the attention kernel. 64-row stripe x 192 cols,
// K=384, BK=32, LDS double-buffered; 37 KB LDS => 4 blocks/CU.
// ---------------------------------------------------------------------------
__global__ __launch_bounds__(256, 4) void proj_kernel(
    const float* __restrict__ x, const __hip_bfloat16* __restrict__ Wt,
    short* __restrict__ Qg, short* __restrict__ Kg, short* __restrict__ VTg)
{
    __shared__ short As[2][64 * 36];    // x tile bf16 [m][kk], stride 36
    __shared__ short Bs[2][192 * 36];   // Wt tile    [n][kk], stride 36

    const int bid = blockIdx.x;
    const int b   = bid & 127;          // batch
    const int q4  = bid >> 7;           // row-quarter of the batch
    const int row0 = b * kT + q4 * 64;  // global x row base

    const int tid  = threadIdx.x;
    const int wave = tid >> 6, lane = tid & 63;
    const int m16  = lane & 15, quad = lane >> 4;
    const short* wt = (const short*)Wt;

    const int arow = tid >> 2, acol = (tid & 3) * 8;
    const float* xr = x + (size_t)(row0 + arow) * kC;

    float4 la[2]; bf16x8 lb[3];
    auto glod = [&](int k0) {
        la[0] = *(const float4*)(xr + k0 + acol);
        la[1] = *(const float4*)(xr + k0 + acol + 4);
#pragma unroll
        for (int p = 0; p < 3; ++p) {
            int c = tid + 256 * p, n = c >> 2, kk = (c & 3) * 8;
            lb[p] = *(const bf16x8*)(wt + (size_t)n * kC + k0 + kk);
        }
    };
    auto swr = [&](int d) {
        *(short4*)&As[d][arow * 36 + acol]     = cvt4(la[0]);
        *(short4*)&As[d][arow * 36 + acol + 4] = cvt4(la[1]);
#pragma unroll
        for (int p = 0; p < 3; ++p) {
            int c = tid + 256 * p, n = c >> 2, kk = (c & 3) * 8;
            *(bf16x8*)&Bs[d][n * 36 + kk] = lb[p];
        }
    };

    f32x4 acc[4][3];
#pragma unroll
    for (int mt = 0; mt < 4; ++mt)
#pragma unroll
        for (int j = 0; j < 3; ++j) acc[mt][j] = f32x4{0.f, 0.f, 0.f, 0.f};

    glod(0);
    swr(0);
    __syncthreads();

    for (int s = 0; s < 12; ++s) {
        const int d = s & 1;
        if (s < 11) glod((s + 1) * 32);            // next tile in flight

        bf16x8 af[4];
#pragma unroll
        for (int mt = 0; mt < 4; ++mt)
            af[mt] = *(const bf16x8*)&As[d][(mt * 16 + m16) * 36 + quad * 8];
#pragma unroll
        for (int j = 0; j < 3; ++j) {
            const bf16x8 bfr =
                *(const bf16x8*)&Bs[d][((wave * 3 + j) * 16 + m16) * 36 + quad * 8];
#pragma unroll
            for (int mt = 0; mt < 4; ++mt)
                acc[mt][j] = __builtin_amdgcn_mfma_f32_16x16x32_bf16(
                    af[mt], bfr, acc[mt][j], 0, 0, 0);
        }

        if (s < 11) swr(d ^ 1);
        __syncthreads();
    }

    // epilogue: C-layout (col = m16, rows = quad*4+r) -> global qkv homes
#pragma unroll
    for (int mt = 0; mt < 4; ++mt) {
        const int mrow = mt * 16 + quad * 4;       // within the 64-row stripe
#pragma unroll
        for (int j = 0; j < 3; ++j) {
            const int nt = wave * 3 + j;           // n-tile 0..11
            const int w  = nt >> 2;                // 0=q, 1=k, 2=v
            const int h  = (nt & 3) * 16 + m16;
            if (w == 2) {
                float4 f = make_float4(acc[mt][j][0], acc[mt][j][1],
                                       acc[mt][j][2], acc[mt][j][3]);
                *(short4*)&VTg[((size_t)b * kH + h) * kT + q4 * 64 + mrow] = cvt4(f);
            } else {
                short* G = (w == 1) ? Kg : Qg;
#pragma unroll
                for (int r = 0; r < 4; ++r)
                    G[((size_t)b * kT + q4 * 64 + mrow + r) * kH + h] = bf1(acc[mt][j][r]);
            }
        }
    }
}

// ---------------------------------------------------------------------------
// Kernel 2: attention, swapped-operand softmax rewrite.
// S' = mfma(qb, ka) transposes the score tile: s (softmax axis) lives in the
// 16 per-lane registers, t = lane&15. Row reduction = 15 in-reg ops + TWO
// shfl_xor (16,32) instead of 32 chained shfls; (m,l) state is scalar.
// O-rescale factors broadcast to t=quad*4+r holders via 4 shfls. P packs as
// 8 bf16x2 words into the per-wave LDS tile (row t=m16, stride 72) and reads
// back with the unchanged b128 A-fragment pattern. V-fragment loads hoisted
// to the top of each iteration (latency hides under softmax). s_setprio(1)
// wraps both MFMA clusters (T5: attention +4-7%). Zero barriers.
// Causal mask (reference: wei[t,s]=k[t]·q[s], keep s<=t) on the diagonal
// tile becomes: quad*4+r (s) > m16 (t) -> -inf.
// ---------------------------------------------------------------------------
__global__ __launch_bounds__(256, 4) void attn_kernel(
    const short* __restrict__ Qg, const short* __restrict__ Kg,
    const short* __restrict__ VTg, float* __restrict__ out)
{
    __shared__ short Pbuf[4][16 * 72];             // per-wave P tile, stride 72

    const int bid = blockIdx.x;
    const int b   = ((bid >> 5) << 3) | (bid & 7); // batch (bid%8 == b%8)
    const int qi  = (bid >> 3) & 3;                // row-quarter

    const int tid  = threadIdx.x;
    const int wave = tid >> 6, lane = tid & 63;
    const int m16  = lane & 15, quad = lane >> 4;
    const int trow0 = qi * 64 + wave * 16;         // this wave's t-band

    const short* Qb = Qg  + (size_t)b * kT * kH;
    const short* Kb = Kg  + (size_t)b * kT * kH;
    const short* Vb = VTg + (size_t)b * kH * kT;
    short* Pb = Pbuf[wave];

    const bf16x8 ka0 = *(const bf16x8*)&Kb[(trow0 + m16) * kH + quad * 8];
    const bf16x8 ka1 = *(const bf16x8*)&Kb[(trow0 + m16) * kH + quad * 8 + 32];

    f32x4 O[4];
#pragma unroll
    for (int i = 0; i < 4; ++i) O[i] = f32x4{0.f, 0.f, 0.f, 0.f};
    float m_ = -INFINITY, l_ = 0.f;

    for (int i = 0; i <= qi; ++i) {
        const bool diag = (i == qi);
        const int jmax = diag ? wave : 3;          // wave-uniform

        // hoist V-fragment loads: no dependency on softmax -> hide latency
        bf16x8 vb[4][2];
#pragma unroll
        for (int ht = 0; ht < 4; ++ht) {
            vb[ht][0] = *(const bf16x8*)&Vb[(ht * 16 + m16) * kT + i * 64 + quad * 8];
            vb[ht][1] = *(const bf16x8*)&Vb[(ht * 16 + m16) * kT + i * 64 + quad * 8 + 32];
        }

        // S'[s][t]: s = i*64 + j*16 + quad*4 + r (regs), t = trow0 + m16
        f32x4 S[4];
        const f32x4 Z = f32x4{0.f, 0.f, 0.f, 0.f};
        __builtin_amdgcn_s_setprio(1);
#pragma unroll
        for (int j = 0; j < 4; ++j) {
            if (j <= jmax) {
                const int s = i * 64 + j * 16 + m16;
                bf16x8 qb0 = *(const bf16x8*)&Qb[s * kH + quad * 8];
                bf16x8 qb1 = *(const bf16x8*)&Qb[s * kH + quad * 8 + 32];
                S[j] = __builtin_amdgcn_mfma_f32_16x16x32_bf16(qb0, ka0, Z, 0, 0, 0);
                S[j] = __builtin_amdgcn_mfma_f32_16x16x32_bf16(qb1, ka1, S[j], 0, 0, 0);
            }
        }
        __builtin_amdgcn_s_setprio(0);
        if (diag) {    // j == jmax tile straddles the diagonal: mask s > t
#pragma unroll
            for (int r = 0; r < 4; ++r)
                if (quad * 4 + r > m16) S[jmax][r] = -INFINITY;
        }

        // in-register row max over this lane's s-slice, then 2 cross-quad shfls
        float rm = -INFINITY;
#pragma unroll
        for (int j = 0; j < 4; ++j)
            if (j <= jmax)
#pragma unroll
                for (int r = 0; r < 4; ++r) rm = fmaxf(rm, S[j][r]);
        rm = fmaxf(rm, __shfl_xor(rm, 16, 64));
        rm = fmaxf(rm, __shfl_xor(rm, 32, 64));

        const float mn = fmaxf(m_, rm);
        const float al = __expf(m_ - mn);
        m_ = mn;

        float P[4][4];
#pragma unroll
        for (int j = 0; j < 4; ++j)
#pragma unroll
            for (int r = 0; r < 4; ++r) P[j][r] = 0.f;
        float rs = 0.f;
#pragma unroll
        for (int j = 0; j < 4; ++j) {
            if (j <= jmax) {
#pragma unroll
                for (int r = 0; r < 4; ++r) {
                    P[j][r] = __expf(S[j][r] - mn);
                    rs += P[j][r];
                }
            }
        }
        rs += __shfl_xor(rs, 16, 64);
        rs += __shfl_xor(rs, 32, 64);
        l_ = l_ * al + rs;

        // broadcast al (held by t=m16 lanes) to the t=quad*4+r accumulators
        float albc[4];
#pragma unroll
        for (int r = 0; r < 4; ++r)
            albc[r] = __shfl(al, (quad << 4) | (quad * 4 + r), 64);
#pragma unroll
        for (int ht = 0; ht < 4; ++ht)
#pragma unroll
            for (int r = 0; r < 4; ++r) O[ht][r] *= albc[r];

        // pack P (8 bf16x2 words) -> Pb row t=m16; read back as A-fragment
#pragma unroll
        for (int j = 0; j < 4; ++j)
#pragma unroll
            for (int p = 0; p < 2; ++p) {
                __hip_bfloat162 w =
                    __float22bfloat162_rn(float2{P[j][2 * p], P[j][2 * p + 1]});
                *(__hip_bfloat162*)&Pb[m16 * 72 + j * 16 + quad * 4 + 2 * p] = w;
            }
        bf16x8 pf0 = *(const bf16x8*)&Pb[m16 * 72 + quad * 8];
        bf16x8 pf1 = *(const bf16x8*)&Pb[m16 * 72 + quad * 8 + 32];

        // O += P @ V
        __builtin_amdgcn_s_setprio(1);
#pragma unroll
        for (int ht = 0; ht < 4; ++ht) {
            O[ht] = __builtin_amdgcn_mfma_f32_16x16x32_bf16(pf0, vb[ht][0], O[ht], 0, 0, 0);
            O[ht] = __builtin_amdgcn_mfma_f32_16x16x32_bf16(pf1, vb[ht][1], O[ht], 0, 0, 0);
        }
        __builtin_amdgcn_s_setprio(0);
    }

    // epilogue: 1/l broadcast from t=m16 holders, scale, store
    float lbc[4];
#pragma unroll
    for (int r = 0; r < 4; ++r)
        lbc[r] = __shfl(l_, (quad << 4) | (quad * 4 + r), 64);
#pragma unroll
    for (int r = 0; r < 4; ++r) {
        const float inv = 1.f / lbc[r];
        const size_t row = (size_t)(b * kT + trow0 + quad * 4 + r);
#pragma unroll
        for (int ht = 0; ht < 4; ++ht)
            out[row * kH + ht * 16 + m16] = O[ht][r] * inv;
    }
}

// ---------------------------------------------------------------------------
extern "C" void kernel_launch(void* const* d_in, const int* in_sizes, int n_in,
                              void* d_out, int out_size, void* d_ws, size_t ws_size,
                              hipStream_t stream) {
    const float* x  = (const float*)d_in[0];
    const float* Wq = (const float*)d_in[1];
    const float* Wk = (const float*)d_in[2];
    const float* Wv = (const float*)d_in[3];
    float* out = (float*)d_out;

    // workspace layout (bf16 as short): Wt | Q | K | VT
    short* base = (short*)d_ws;
    __hip_bfloat16* Wt = (__hip_bfloat16*)base;            // 192*384 = 73728
    short* Qg  = base + 73728;                             // 128*256*64
    short* Kg  = Qg + (size_t)kB * kT * kH;
    short* VTg = Kg + (size_t)kB * kT * kH;

    prep_kernel<<<(192 * kC) / 256, 256, 0, stream>>>(Wq, Wk, Wv, Wt);
    proj_kernel<<<dim3(512), 256, 0, stream>>>(x, Wt, Qg, Kg, VTg);
    attn_kernel<<<dim3(512), 256, 0, stream>>>(Qg, Kg, VTg, out);
}

// Round 5
// 114.361 us; speedup vs baseline: 1.0703x; 1.0703x over previous
//
#include <hip/hip_runtime.h>
#include <hip/hip_bf16.h>
#include <math.h>

constexpr int kB = 128;
constexpr int kT = 256;
constexpr int kC = 384;
constexpr int kH = 64;

using bf16x8 = __attribute__((ext_vector_type(8))) short;  // 8 bf16 = 4 VGPRs
using f32x4  = __attribute__((ext_vector_type(4))) float;

union BF4 { short4 s; __hip_bfloat162 h[2]; };

__device__ inline short4 cvt4(float4 a) {
    BF4 u;
    u.h[0] = __float22bfloat162_rn(float2{a.x, a.y});
    u.h[1] = __float22bfloat162_rn(float2{a.z, a.w});
    return u.s;
}
__device__ inline short bf1(float f) {
    __hip_bfloat16 h = __float2bfloat16(f);
    return *(short*)&h;
}

// ---------------------------------------------------------------------------
// Kernel 0: Wt[n][k] bf16, n in [0,192) = (w*64+h), k in [0,384).
// Wk rows pre-scaled by 384^-0.5 (k only feeds scores).
// ---------------------------------------------------------------------------
__global__ void prep_kernel(const float* __restrict__ Wq,
                            const float* __restrict__ Wk,
                            const float* __restrict__ Wv,
                            __hip_bfloat16* __restrict__ Wt) {
    int idx = blockIdx.x * 256 + threadIdx.x;     // [0, 192*384)
    int n = idx / kC, c = idx % kC;
    int w = n >> 6, h = n & 63;
    const float* W = (w == 0) ? Wq : (w == 1) ? Wk : Wv;
    float val = W[c * kH + h];
    if (w == 1) val *= 0.051031036307982884f;     // 384^-0.5
    Wt[idx] = __float2bfloat16(val);
}

// ---------------------------------------------------------------------------
// Fused kernel — R1 structure (best measured: fused 49.6 us, dur 111.7) with
// two serial-path cuts, everything else identical:
//  (a) Phase 1 is now a 2-DEEP register pipeline: tile s+2 is loaded to regs
//      while tile s+1 (loaded a full step earlier) is written to LDS, so the
//      global-load latency is covered by an entire K-step instead of being
//      exposed inside each step (R2 validated the schedule; its regression
//      was the 64-VGPR cap from __launch_bounds__(1024,4), not the pipeline —
//      here at (512,2) the cap is 256 and no spills occur).
//  (b) Phase 2 uses the swapped-operand softmax (R4, harness-verified):
//      S' = mfma(qb, ka) puts the softmax axis s in registers, t = lane&15.
//      Row reduction = in-reg ops + TWO shfl_xor (16,32) instead of 32
//      chained shfls; scalar (m,l); al/l broadcast via 4 shfls; P packed as
//      bf16x2 into the dead As buffer (stride 72); s_setprio around MFMA.
// Block = (b, half), 512 threads; XCD pair swizzle; dead-K skip; LDS 150 KB.
// ---------------------------------------------------------------------------
__global__ __launch_bounds__(512, 2) void fused_kernel(
    const float* __restrict__ x, const __hip_bfloat16* __restrict__ Wt,
    float* __restrict__ out)
{
    __shared__ short Qs[256 * 72];      // [s][h]
    __shared__ short Ks[128 * 72];      // [t-t0][h]
    __shared__ short VTs[64 * 264];     // [h][s]
    __shared__ short As[2][256 * 36];   // x tile bf16 [m][kk], stride 36
    __shared__ short Bs[2][192 * 36];   // Wt tile    [n][kk], stride 36

    const int bid  = blockIdx.x;
    const int b    = ((bid >> 4) << 3) | (bid & 7);   // batch
    const int half = ((bid >> 3) & 1) ^ 1;            // heavy (1) first
    const int t0   = half * 128;

    const int tid  = threadIdx.x;
    const int wave = tid >> 6, lane = tid & 63;
    const int m16  = lane & 15, quad = lane >> 4;
    const int wm = wave & 1, wn = wave >> 1;       // m-half, 3-n-tile slice
    const short* wt = (const short*)Wt;
    const float* xb = x + (size_t)b * kT * kC;

    // wave-uniform activity masks for the light half (M = 128)
    const bool mfmaAct = (half == 1) || (wm == 0);

    // dead-K: heavy half's rows 0-127 K-projection is discarded -> skip
    bool kskip[3];
#pragma unroll
    for (int j = 0; j < 3; ++j) {
        const int nt = wn * 3 + j;
        kskip[j] = (half == 1) && (wm == 0) && (nt >= 4) && (nt < 8);
    }

    // ---------------- Phase 1: projection (2-deep pipeline) ----------------
    // A staging: row = tid>>1 (waves 0-3 -> rows 0-127, wave-uniform light
    // skip), 16-col fp32 chunk (tid&1)*16.
    const int arow = tid >> 1, acol = (tid & 1) * 16;
    const bool aAct = (half == 1) || (arow < 128);

    float4 la0[4], la1[4]; bf16x8 lb0a, lb0b, lb1a, lb1b;
    auto glod = [&](float4* la, bf16x8& lba, bf16x8& lbb, int k0) {
        if (aAct) {
#pragma unroll
            for (int i = 0; i < 4; ++i)
                la[i] = *(const float4*)(xb + (size_t)arow * kC + k0 + acol + 4 * i);
        }
        {
            int n = tid >> 2, kk = (tid & 3) * 8;
            lba = *(const bf16x8*)(wt + (size_t)n * kC + k0 + kk);
        }
        if (tid < 256) {
            int c = tid + 512;
            int n = c >> 2, kk = (c & 3) * 8;
            lbb = *(const bf16x8*)(wt + (size_t)n * kC + k0 + kk);
        }
    };
    auto swr = [&](int d, const float4* la, const bf16x8& lba, const bf16x8& lbb) {
        if (aAct) {
#pragma unroll
            for (int i = 0; i < 4; ++i)
                *(short4*)&As[d][arow * 36 + acol + 4 * i] = cvt4(la[i]);
        }
        {
            int n = tid >> 2, kk = (tid & 3) * 8;
            *(bf16x8*)&Bs[d][n * 36 + kk] = lba;
        }
        if (tid < 256) {
            int c = tid + 512;
            int n = c >> 2, kk = (c & 3) * 8;
            *(bf16x8*)&Bs[d][n * 36 + kk] = lbb;
        }
    };

    f32x4 acc[8][3];
#pragma unroll
    for (int mt = 0; mt < 8; ++mt)
#pragma unroll
        for (int j = 0; j < 3; ++j) acc[mt][j] = f32x4{0.f, 0.f, 0.f, 0.f};

    auto mstep = [&](int d) {
        if (!mfmaAct) return;
        bf16x8 af[8];
#pragma unroll
        for (int mt = 0; mt < 8; ++mt)
            af[mt] = *(const bf16x8*)&As[d][(wm * 128 + mt * 16 + m16) * 36 + quad * 8];
#pragma unroll
        for (int j = 0; j < 3; ++j) {
            if (!kskip[j]) {
                const bf16x8 bfr =
                    *(const bf16x8*)&Bs[d][((wn * 3 + j) * 16 + m16) * 36 + quad * 8];
#pragma unroll
                for (int mt = 0; mt < 8; ++mt)
                    acc[mt][j] = __builtin_amdgcn_mfma_f32_16x16x32_bf16(
                        af[mt], bfr, acc[mt][j], 0, 0, 0);
            }
        }
    };

    // prologue: tiles 0,1 in regs; tile 0 -> LDS buf0
    glod(la0, lb0a, lb0b, 0);
    glod(la1, lb1a, lb1b, 32);
    swr(0, la0, lb0a, lb0b);
    __syncthreads();

    for (int s = 0; s < 12; s += 2) {
        // even: compute tile s (buf0); load tile s+2; write buf1 <- tile s+1
        if (s < 10) glod(la0, lb0a, lb0b, (s + 2) * 32);
        mstep(0);
        swr(1, la1, lb1a, lb1b);
        __syncthreads();
        // odd: compute tile s+1 (buf1); load tile s+3; write buf0 <- tile s+2
        if (s + 1 < 10) glod(la1, lb1a, lb1b, (s + 3) * 32);
        mstep(1);
        if (s + 1 < 11) swr(0, la0, lb0a, lb0b);
        __syncthreads();
    }

    // epilogue: C-layout (col = m16 in-tile, rows = quad*4+r) -> LDS homes
    if (mfmaAct) {
#pragma unroll
        for (int mt = 0; mt < 8; ++mt) {
            const int mbase = wm * 128 + mt * 16 + quad * 4;
#pragma unroll
            for (int j = 0; j < 3; ++j) {
                const int nt = wn * 3 + j;             // n-tile 0..11
                const int w  = nt >> 2;                // 0=q, 1=k, 2=v
                const int h  = (nt & 3) * 16 + m16;
                if (w == 2) {
                    float4 f = make_float4(acc[mt][j][0], acc[mt][j][1],
                                           acc[mt][j][2], acc[mt][j][3]);
                    *(short4*)&VTs[h * 264 + mbase] = cvt4(f);   // s = mbase..+3
                } else if (w == 1) {
                    if ((mbase >> 7) == half) {        // rows [t0, t0+128)
#pragma unroll
                        for (int r = 0; r < 4; ++r)
                            Ks[(mbase + r - t0) * 72 + h] = bf1(acc[mt][j][r]);
                    }
                } else {
#pragma unroll
                    for (int r = 0; r < 4; ++r)
                        Qs[(mbase + r) * 72 + h] = bf1(acc[mt][j][r]);
                }
            }
        }
    }
    __syncthreads();   // phase boundary: Qs/Ks/VTs all visible

    // -------- Phase 2: attention, swapped-operand softmax (barrier-free) ----
    const int wband = t0 + wave * 16;              // this wave's t-band
    short* Pb = &As[0][0] + wave * 1152;           // dead As: 16x72 bf16/wave

    // K fragment as B-operand: row t = wband+m16, h-chunk = quad*8
    const bf16x8 ka0 = *(const bf16x8*)&Ks[(wave * 16 + m16) * 72 + quad * 8];
    const bf16x8 ka1 = *(const bf16x8*)&Ks[(wave * 16 + m16) * 72 + quad * 8 + 32];

    f32x4 O[4];
#pragma unroll
    for (int i = 0; i < 4; ++i) O[i] = f32x4{0.f, 0.f, 0.f, 0.f};
    float m_ = -INFINITY, l_ = 0.f;

    const int ilast = wband >> 6;
    for (int i = 0; i <= ilast; ++i) {
        const bool diag = (i == ilast);
        const int jmax = diag ? (wave & 3) : 3;    // wave-uniform

        // S'[s][t]: s = i*64 + j*16 + quad*4 + r (regs), t = wband + m16
        f32x4 S[4];
        const f32x4 Z = f32x4{0.f, 0.f, 0.f, 0.f};
        __builtin_amdgcn_s_setprio(1);
#pragma unroll
        for (int j = 0; j < 4; ++j) {
            if (j <= jmax) {
                const int s = i * 64 + j * 16 + m16;
                bf16x8 qb0 = *(const bf16x8*)&Qs[s * 72 + quad * 8];
                bf16x8 qb1 = *(const bf16x8*)&Qs[s * 72 + quad * 8 + 32];
                S[j] = __builtin_amdgcn_mfma_f32_16x16x32_bf16(qb0, ka0, Z, 0, 0, 0);
                S[j] = __builtin_amdgcn_mfma_f32_16x16x32_bf16(qb1, ka1, S[j], 0, 0, 0);
            }
        }
        __builtin_amdgcn_s_setprio(0);
        if (diag) {    // j == jmax tile straddles the diagonal: mask s > t
#pragma unroll
            for (int r = 0; r < 4; ++r)
                if (quad * 4 + r > m16) S[jmax][r] = -INFINITY;
        }

        // in-register max over this lane's s-slice, then 2 cross-quad shfls
        float rm = -INFINITY;
#pragma unroll
        for (int j = 0; j < 4; ++j)
            if (j <= jmax)
#pragma unroll
                for (int r = 0; r < 4; ++r) rm = fmaxf(rm, S[j][r]);
        rm = fmaxf(rm, __shfl_xor(rm, 16, 64));
        rm = fmaxf(rm, __shfl_xor(rm, 32, 64));

        const float mn = fmaxf(m_, rm);
        const float al = __expf(m_ - mn);
        m_ = mn;

        float P[4][4];
#pragma unroll
        for (int j = 0; j < 4; ++j)
#pragma unroll
            for (int r = 0; r < 4; ++r) P[j][r] = 0.f;
        float rs = 0.f;
#pragma unroll
        for (int j = 0; j < 4; ++j) {
            if (j <= jmax) {
#pragma unroll
                for (int r = 0; r < 4; ++r) {
                    P[j][r] = __expf(S[j][r] - mn);
                    rs += P[j][r];
                }
            }
        }
        rs += __shfl_xor(rs, 16, 64);
        rs += __shfl_xor(rs, 32, 64);
        l_ = l_ * al + rs;

        // broadcast al (held by t=m16 lanes) to the t=quad*4+r accumulators
        float albc[4];
#pragma unroll
        for (int r = 0; r < 4; ++r)
            albc[r] = __shfl(al, (quad << 4) | (quad * 4 + r), 64);
#pragma unroll
        for (int ht = 0; ht < 4; ++ht)
#pragma unroll
            for (int r = 0; r < 4; ++r) O[ht][r] *= albc[r];

        // pack P (8 bf16x2 words) -> Pb row t=m16; read back as A-fragment
#pragma unroll
        for (int j = 0; j < 4; ++j)
#pragma unroll
            for (int p = 0; p < 2; ++p) {
                __hip_bfloat162 w =
                    __float22bfloat162_rn(float2{P[j][2 * p], P[j][2 * p + 1]});
                *(__hip_bfloat162*)&Pb[m16 * 72 + j * 16 + quad * 4 + 2 * p] = w;
            }
        bf16x8 pf0 = *(const bf16x8*)&Pb[m16 * 72 + quad * 8];
        bf16x8 pf1 = *(const bf16x8*)&Pb[m16 * 72 + quad * 8 + 32];

        // O += P @ V  (V from LDS, [h][s])
        __builtin_amdgcn_s_setprio(1);
#pragma unroll
        for (int ht = 0; ht < 4; ++ht) {
            bf16x8 vb0 = *(const bf16x8*)&VTs[(ht * 16 + m16) * 264 + i * 64 + quad * 8];
            bf16x8 vb1 = *(const bf16x8*)&VTs[(ht * 16 + m16) * 264 + i * 64 + quad * 8 + 32];
            O[ht] = __builtin_amdgcn_mfma_f32_16x16x32_bf16(pf0, vb0, O[ht], 0, 0, 0);
            O[ht] = __builtin_amdgcn_mfma_f32_16x16x32_bf16(pf1, vb1, O[ht], 0, 0, 0);
        }
        __builtin_amdgcn_s_setprio(0);
    }

    // epilogue: 1/l broadcast from t=m16 holders, scale, store
    float lbc[4];
#pragma unroll
    for (int r = 0; r < 4; ++r)
        lbc[r] = __shfl(l_, (quad << 4) | (quad * 4 + r), 64);
#pragma unroll
    for (int r = 0; r < 4; ++r) {
        const float inv = 1.f / lbc[r];
        const size_t row = (size_t)(b * kT + wband + quad * 4 + r);
#pragma unroll
        for (int ht = 0; ht < 4; ++ht)
            out[row * kH + ht * 16 + m16] = O[ht][r] * inv;
    }
}

// ---------------------------------------------------------------------------
extern "C" void kernel_launch(void* const* d_in, const int* in_sizes, int n_in,
                              void* d_out, int out_size, void* d_ws, size_t ws_size,
                              hipStream_t stream) {
    const float* x  = (const float*)d_in[0];
    const float* Wq = (const float*)d_in[1];
    const float* Wk = (const float*)d_in[2];
    const float* Wv = (const float*)d_in[3];
    float* out = (float*)d_out;

    __hip_bfloat16* Wt = (__hip_bfloat16*)d_ws;    // 147 KB [n][k]

    prep_kernel<<<(192 * kC) / 256, 256, 0, stream>>>(Wq, Wk, Wv, Wt);
    fused_kernel<<<dim3(256), 512, 0, stream>>>(x, Wt, out);
}

// Round 6
// 110.702 us; speedup vs baseline: 1.1057x; 1.0331x over previous
//
#include <hip/hip_runtime.h>
#include <hip/hip_bf16.h>
#include <math.h>

constexpr int kB = 128;
constexpr int kT = 256;
constexpr int kC = 384;
constexpr int kH = 64;

using bf16x8 = __attribute__((ext_vector_type(8))) short;  // 8 bf16 = 4 VGPRs
using f32x4  = __attribute__((ext_vector_type(4))) float;

union BF4 { short4 s; __hip_bfloat162 h[2]; };

__device__ inline short4 cvt4(float4 a) {
    BF4 u;
    u.h[0] = __float22bfloat162_rn(float2{a.x, a.y});
    u.h[1] = __float22bfloat162_rn(float2{a.z, a.w});
    return u.s;
}
__device__ inline short bf1(float f) {
    __hip_bfloat16 h = __float2bfloat16(f);
    return *(short*)&h;
}

// ---------------------------------------------------------------------------
// Kernel 0: Wt[n][k] bf16, n in [0,192) = (w*64+h), k in [0,384).
// Wk rows pre-scaled by 384^-0.5 (k only feeds scores).
// ---------------------------------------------------------------------------
__global__ void prep_kernel(const float* __restrict__ Wq,
                            const float* __restrict__ Wk,
                            const float* __restrict__ Wv,
                            __hip_bfloat16* __restrict__ Wt) {
    int idx = blockIdx.x * 256 + threadIdx.x;     // [0, 192*384)
    int n = idx / kC, c = idx % kC;
    int w = n >> 6, h = n & 63;
    const float* W = (w == 0) ? Wq : (w == 1) ? Wk : Wv;
    float val = W[c * kH + h];
    if (w == 1) val *= 0.051031036307982884f;     // 384^-0.5
    Wt[idx] = __float2bfloat16(val);
}

// ---------------------------------------------------------------------------
// Fused kernel — R5 phase 1 (2-deep register pipeline) unchanged; phase 2
// rewritten as BATCH softmax (this round's only delta):
//   The flash loop's inter-iteration serial chain (QK^T -> reduce -> rescale
//   -> P roundtrip -> PV, carried through m_/l_/O) is gone. All S-tiles for
//   the wave's t-band fit in registers (S[4][4] f32x4 = 64 VGPR, statically
//   indexed, wave-uniform guards), so: compute ALL QK^T tiles back-to-back,
//   ONE max reduce (2 shfl_xor), ONE in-place exp pass, ONE sum (2 shfl_xor),
//   then the PV loop. No online rescale, no al broadcasts, exact softmax.
// Block = (b, half), 512 threads; XCD pair swizzle; dead-K skip; LDS 150 KB.
// ---------------------------------------------------------------------------
__global__ __launch_bounds__(512, 2) void fused_kernel(
    const float* __restrict__ x, const __hip_bfloat16* __restrict__ Wt,
    float* __restrict__ out)
{
    __shared__ short Qs[256 * 72];      // [s][h]
    __shared__ short Ks[128 * 72];      // [t-t0][h]
    __shared__ short VTs[64 * 264];     // [h][s]
    __shared__ short As[2][256 * 36];   // x tile bf16 [m][kk], stride 36
    __shared__ short Bs[2][192 * 36];   // Wt tile    [n][kk], stride 36

    const int bid  = blockIdx.x;
    const int b    = ((bid >> 4) << 3) | (bid & 7);   // batch
    const int half = ((bid >> 3) & 1) ^ 1;            // heavy (1) first
    const int t0   = half * 128;

    const int tid  = threadIdx.x;
    const int wave = tid >> 6, lane = tid & 63;
    const int m16  = lane & 15, quad = lane >> 4;
    const int wm = wave & 1, wn = wave >> 1;       // m-half, 3-n-tile slice
    const short* wt = (const short*)Wt;
    const float* xb = x + (size_t)b * kT * kC;

    // wave-uniform activity masks for the light half (M = 128)
    const bool mfmaAct = (half == 1) || (wm == 0);

    // dead-K: heavy half's rows 0-127 K-projection is discarded -> skip
    bool kskip[3];
#pragma unroll
    for (int j = 0; j < 3; ++j) {
        const int nt = wn * 3 + j;
        kskip[j] = (half == 1) && (wm == 0) && (nt >= 4) && (nt < 8);
    }

    // ---------------- Phase 1: projection (2-deep pipeline) ----------------
    const int arow = tid >> 1, acol = (tid & 1) * 16;
    const bool aAct = (half == 1) || (arow < 128);

    float4 la0[4], la1[4]; bf16x8 lb0a, lb0b, lb1a, lb1b;
    auto glod = [&](float4* la, bf16x8& lba, bf16x8& lbb, int k0) {
        if (aAct) {
#pragma unroll
            for (int i = 0; i < 4; ++i)
                la[i] = *(const float4*)(xb + (size_t)arow * kC + k0 + acol + 4 * i);
        }
        {
            int n = tid >> 2, kk = (tid & 3) * 8;
            lba = *(const bf16x8*)(wt + (size_t)n * kC + k0 + kk);
        }
        if (tid < 256) {
            int c = tid + 512;
            int n = c >> 2, kk = (c & 3) * 8;
            lbb = *(const bf16x8*)(wt + (size_t)n * kC + k0 + kk);
        }
    };
    auto swr = [&](int d, const float4* la, const bf16x8& lba, const bf16x8& lbb) {
        if (aAct) {
#pragma unroll
            for (int i = 0; i < 4; ++i)
                *(short4*)&As[d][arow * 36 + acol + 4 * i] = cvt4(la[i]);
        }
        {
            int n = tid >> 2, kk = (tid & 3) * 8;
            *(bf16x8*)&Bs[d][n * 36 + kk] = lba;
        }
        if (tid < 256) {
            int c = tid + 512;
            int n = c >> 2, kk = (c & 3) * 8;
            *(bf16x8*)&Bs[d][n * 36 + kk] = lbb;
        }
    };

    f32x4 acc[8][3];
#pragma unroll
    for (int mt = 0; mt < 8; ++mt)
#pragma unroll
        for (int j = 0; j < 3; ++j) acc[mt][j] = f32x4{0.f, 0.f, 0.f, 0.f};

    auto mstep = [&](int d) {
        if (!mfmaAct) return;
        bf16x8 af[8];
#pragma unroll
        for (int mt = 0; mt < 8; ++mt)
            af[mt] = *(const bf16x8*)&As[d][(wm * 128 + mt * 16 + m16) * 36 + quad * 8];
#pragma unroll
        for (int j = 0; j < 3; ++j) {
            if (!kskip[j]) {
                const bf16x8 bfr =
                    *(const bf16x8*)&Bs[d][((wn * 3 + j) * 16 + m16) * 36 + quad * 8];
#pragma unroll
                for (int mt = 0; mt < 8; ++mt)
                    acc[mt][j] = __builtin_amdgcn_mfma_f32_16x16x32_bf16(
                        af[mt], bfr, acc[mt][j], 0, 0, 0);
            }
        }
    };

    // prologue: tiles 0,1 in regs; tile 0 -> LDS buf0
    glod(la0, lb0a, lb0b, 0);
    glod(la1, lb1a, lb1b, 32);
    swr(0, la0, lb0a, lb0b);
    __syncthreads();

    for (int s = 0; s < 12; s += 2) {
        // even: compute tile s (buf0); load tile s+2; write buf1 <- tile s+1
        if (s < 10) glod(la0, lb0a, lb0b, (s + 2) * 32);
        mstep(0);
        swr(1, la1, lb1a, lb1b);
        __syncthreads();
        // odd: compute tile s+1 (buf1); load tile s+3; write buf0 <- tile s+2
        if (s + 1 < 10) glod(la1, lb1a, lb1b, (s + 3) * 32);
        mstep(1);
        if (s + 1 < 11) swr(0, la0, lb0a, lb0b);
        __syncthreads();
    }

    // epilogue: C-layout (col = m16 in-tile, rows = quad*4+r) -> LDS homes
    if (mfmaAct) {
#pragma unroll
        for (int mt = 0; mt < 8; ++mt) {
            const int mbase = wm * 128 + mt * 16 + quad * 4;
#pragma unroll
            for (int j = 0; j < 3; ++j) {
                const int nt = wn * 3 + j;             // n-tile 0..11
                const int w  = nt >> 2;                // 0=q, 1=k, 2=v
                const int h  = (nt & 3) * 16 + m16;
                if (w == 2) {
                    float4 f = make_float4(acc[mt][j][0], acc[mt][j][1],
                                           acc[mt][j][2], acc[mt][j][3]);
                    *(short4*)&VTs[h * 264 + mbase] = cvt4(f);   // s = mbase..+3
                } else if (w == 1) {
                    if ((mbase >> 7) == half) {        // rows [t0, t0+128)
#pragma unroll
                        for (int r = 0; r < 4; ++r)
                            Ks[(mbase + r - t0) * 72 + h] = bf1(acc[mt][j][r]);
                    }
                } else {
#pragma unroll
                    for (int r = 0; r < 4; ++r)
                        Qs[(mbase + r) * 72 + h] = bf1(acc[mt][j][r]);
                }
            }
        }
    }
    __syncthreads();   // phase boundary: Qs/Ks/VTs all visible

    // -------- Phase 2: attention, BATCH softmax (barrier-free) ----------
    const int wband = t0 + wave * 16;              // this wave's t-band
    short* Pb = &As[0][0] + wave * 1152;           // dead As: 16x72 bf16/wave

    const bf16x8 ka0 = *(const bf16x8*)&Ks[(wave * 16 + m16) * 72 + quad * 8];
    const bf16x8 ka1 = *(const bf16x8*)&Ks[(wave * 16 + m16) * 72 + quad * 8 + 32];

    const int ilast = wband >> 6;                  // wave-uniform
    const int jmaxd = wave & 3;                    // diag-tile jmax

    // all S' tiles in registers: S[i][j][r], s = i*64+j*16+quad*4+r, t = m16
    f32x4 S[4][4];
    const f32x4 Z = f32x4{0.f, 0.f, 0.f, 0.f};
#pragma unroll
    for (int i = 0; i < 4; ++i)
#pragma unroll
        for (int j = 0; j < 4; ++j) S[i][j] = Z;

    __builtin_amdgcn_s_setprio(1);
#pragma unroll
    for (int i = 0; i < 4; ++i) {
        if (i <= ilast) {
#pragma unroll
            for (int j = 0; j < 4; ++j) {
                if (i < ilast || j <= jmaxd) {
                    const int s = i * 64 + j * 16 + m16;
                    bf16x8 qb0 = *(const bf16x8*)&Qs[s * 72 + quad * 8];
                    bf16x8 qb1 = *(const bf16x8*)&Qs[s * 72 + quad * 8 + 32];
                    S[i][j] = __builtin_amdgcn_mfma_f32_16x16x32_bf16(qb0, ka0, S[i][j], 0, 0, 0);
                    S[i][j] = __builtin_amdgcn_mfma_f32_16x16x32_bf16(qb1, ka1, S[i][j], 0, 0, 0);
                }
            }
        }
    }
    __builtin_amdgcn_s_setprio(0);

    // diagonal mask on tile (ilast, jmaxd): s > t -> -inf   (static indices)
#pragma unroll
    for (int i = 0; i < 4; ++i)
#pragma unroll
        for (int j = 0; j < 4; ++j)
            if (i == ilast && j == jmaxd) {
#pragma unroll
                for (int r = 0; r < 4; ++r)
                    if (quad * 4 + r > m16) S[i][j][r] = -INFINITY;
            }

    // ONE global max over the whole row (t = wband + m16)
    float rm = -INFINITY;
#pragma unroll
    for (int i = 0; i < 4; ++i)
#pragma unroll
        for (int j = 0; j < 4; ++j)
            if (i <= ilast && (i < ilast || j <= jmaxd))
#pragma unroll
                for (int r = 0; r < 4; ++r) rm = fmaxf(rm, S[i][j][r]);
    rm = fmaxf(rm, __shfl_xor(rm, 16, 64));
    rm = fmaxf(rm, __shfl_xor(rm, 32, 64));

    // ONE exp pass in place + row sum  (masked slots: exp(-inf)=0; invalid
    // tiles stay Z and are skipped -> pack as zeros)
    float l_ = 0.f;
#pragma unroll
    for (int i = 0; i < 4; ++i)
#pragma unroll
        for (int j = 0; j < 4; ++j)
            if (i <= ilast && (i < ilast || j <= jmaxd))
#pragma unroll
                for (int r = 0; r < 4; ++r) {
                    const float e = __expf(S[i][j][r] - rm);
                    S[i][j][r] = e;
                    l_ += e;
                }
    l_ += __shfl_xor(l_, 16, 64);
    l_ += __shfl_xor(l_, 32, 64);

    // PV: per i-tile, pack P -> Pb, read back as A-fragment, 8 MFMAs
    f32x4 O[4];
#pragma unroll
    for (int i = 0; i < 4; ++i) O[i] = f32x4{0.f, 0.f, 0.f, 0.f};

#pragma unroll
    for (int i = 0; i < 4; ++i) {
        if (i <= ilast) {
#pragma unroll
            for (int j = 0; j < 4; ++j)
#pragma unroll
                for (int p = 0; p < 2; ++p) {
                    __hip_bfloat162 w = __float22bfloat162_rn(
                        float2{S[i][j][2 * p], S[i][j][2 * p + 1]});
                    *(__hip_bfloat162*)&Pb[m16 * 72 + j * 16 + quad * 4 + 2 * p] = w;
                }
            bf16x8 pf0 = *(const bf16x8*)&Pb[m16 * 72 + quad * 8];
            bf16x8 pf1 = *(const bf16x8*)&Pb[m16 * 72 + quad * 8 + 32];

            __builtin_amdgcn_s_setprio(1);
#pragma unroll
            for (int ht = 0; ht < 4; ++ht) {
                bf16x8 vb0 = *(const bf16x8*)&VTs[(ht * 16 + m16) * 264 + i * 64 + quad * 8];
                bf16x8 vb1 = *(const bf16x8*)&VTs[(ht * 16 + m16) * 264 + i * 64 + quad * 8 + 32];
                O[ht] = __builtin_amdgcn_mfma_f32_16x16x32_bf16(pf0, vb0, O[ht], 0, 0, 0);
                O[ht] = __builtin_amdgcn_mfma_f32_16x16x32_bf16(pf1, vb1, O[ht], 0, 0, 0);
            }
            __builtin_amdgcn_s_setprio(0);
        }
    }

    // epilogue: 1/l broadcast from t=m16 holders, scale, store
    float lbc[4];
#pragma unroll
    for (int r = 0; r < 4; ++r)
        lbc[r] = __shfl(l_, (quad << 4) | (quad * 4 + r), 64);
#pragma unroll
    for (int r = 0; r < 4; ++r) {
        const float inv = 1.f / lbc[r];
        const size_t row = (size_t)(b * kT + wband + quad * 4 + r);
#pragma unroll
        for (int ht = 0; ht < 4; ++ht)
            out[row * kH + ht * 16 + m16] = O[ht][r] * inv;
    }
}

// ---------------------------------------------------------------------------
extern "C" void kernel_launch(void* const* d_in, const int* in_sizes, int n_in,
                              void* d_out, int out_size, void* d_ws, size_t ws_size,
                              hipStream_t stream) {
    const float* x  = (const float*)d_in[0];
    const float* Wq = (const float*)d_in[1];
    const float* Wk = (const float*)d_in[2];
    const float* Wv = (const float*)d_in[3];
    float* out = (float*)d_out;

    __hip_bfloat16* Wt = (__hip_bfloat16*)d_ws;    // 147 KB [n][k]

    prep_kernel<<<(192 * kC) / 256, 256, 0, stream>>>(Wq, Wk, Wv, Wt);
    fused_kernel<<<dim3(256), 512, 0, stream>>>(x, Wt, out);
}